// Round 20
// baseline (536.699 us; speedup 1.0000x reference)
//
#include <hip/hip_runtime.h>
#include <math.h>

#define NPTS 4096
#define BATCH 8
#define HIDD 512
#define ROWS 32768
#define R_ATT2 0.04f
#define INV_SQRT_D 0.08838834764831845f

typedef unsigned short u16;
typedef unsigned int u32;
typedef __attribute__((ext_vector_type(8))) short s8v;
typedef __attribute__((ext_vector_type(4))) float f4v;

__device__ __forceinline__ float u2f(u16 v) { return __uint_as_float(((u32)v) << 16); }
__device__ __forceinline__ u16 f2u(float f) {         // RNE fp32->bf16
  u32 u = __float_as_uint(f);
  return (u16)((u + 0x7fffu + ((u >> 16) & 1u)) >> 16);
}
// trunc-pack two fp32 into packed bf16 pair (1 lshr + 1 and_or)
__device__ __forceinline__ u32 packtrunc(float x0, float x1) {
  return (__float_as_uint(x1) & 0xFFFF0000u) | (__float_as_uint(x0) >> 16);
}

// ---------------------------------------------------------------------------
// G = wq^T @ wk (3x3)
__global__ void gram_k(const float* __restrict__ wq, const float* __restrict__ wk,
                       float* __restrict__ G) {
  int ab = threadIdx.x;
  if (ab < 9) {
    int a = ab / 3, b = ab % 3;
    float s = 0.f;
    for (int d = 0; d < 128; ++d) s = fmaf(wq[d * 3 + a], wk[d * 3 + b], s);
    G[ab] = s;
  }
}

// Fused per-stage prep: zw (wave-per-output) + ubuf/w1abf/w2bf conversions.
__global__ __launch_bounds__(256) void prep2_k(
    const float* __restrict__ z, const float* __restrict__ w1, int ldw,
    const float* __restrict__ b1, const float* __restrict__ w2,
    float* __restrict__ zwbuf, float* __restrict__ ubuf,
    u16* __restrict__ w1abf, u16* __restrict__ w2bf, int doW1a) {
  int wid = blockIdx.x * 4 + (threadIdx.x >> 6);   // 0..4095
  int lane = threadIdx.x & 63;
  {
    int b = wid >> 9, c = wid & 511;
    const float* zr = z + b * 512;
    const float* wr = w1 + (size_t)c * ldw;
    float acc = 0.f;
#pragma unroll
    for (int k = lane; k < 512; k += 64) acc = fmaf(zr[k], wr[k], acc);
#pragma unroll
    for (int off = 32; off; off >>= 1) acc += __shfl_down(acc, off);
    if (lane == 0) zwbuf[wid] = acc + b1[c];
  }
  int idx = blockIdx.x * 256 + threadIdx.x;        // 1024 blocks = 262144
  if (idx < 1536) {
    int a = idx >> 9, c = idx & 511;
    ubuf[idx] = w1[(size_t)c * ldw + 512 + a];
  }
  if (doW1a && idx < 65536) {
    int n = idx >> 7, k = idx & 127;
    w1abf[idx] = f2u(w1[(size_t)n * 643 + 515 + k]);
  }
  w2bf[idx] = f2u(w2[idx]);
}

// stage0 layer1: wave-per-row, vectorized loads + uint4 trunc-pack store
__global__ __launch_bounds__(256) void s0l1_k(const float* __restrict__ tmpl,
                                              const float* __restrict__ u,
                                              const float* __restrict__ zw,
                                              u16* __restrict__ h) {
  int wid = blockIdx.x * 4 + (threadIdx.x >> 6);   // row 0..32767
  int lane = threadIdx.x & 63;
  int b = wid >> 12, n = wid & (NPTS - 1);
  float tx = tmpl[n * 3], ty = tmpl[n * 3 + 1], tz = tmpl[n * 3 + 2];
  int c0 = lane * 8;
  const float* zr = zw + b * 512 + c0;
  const float* u0 = u + c0;
  const float* u1 = u + 512 + c0;
  const float* u2 = u + 1024 + c0;
  u32 outw[4];
#pragma unroll
  for (int t = 0; t < 4; ++t) {
    float v0 = zr[2 * t] + tx * u0[2 * t] + ty * u1[2 * t] + tz * u2[2 * t];
    float v1 = zr[2 * t + 1] + tx * u0[2 * t + 1] + ty * u1[2 * t + 1] + tz * u2[2 * t + 1];
    outw[t] = packtrunc(v0, v1);
  }
  *(uint4*)(h + (size_t)wid * 512 + c0) = *(const uint4*)outw;
}

// ---------------------------------------------------------------------------
// MFMA GEMM (BK=32, 16 KB LDS — occupancy-optimal).
// Fused BN-stats epilogue; optional fused BN+ReLU on A (trunc-pack).
template <bool MODE1, bool APPLY_A>
__global__ __launch_bounds__(256) void gemm_mfma_k(
    const u16* __restrict__ A, int lda, const u16* __restrict__ B, int ldb, int K,
    const float* __restrict__ bias, const float* __restrict__ zw,
    const float* __restrict__ u, const float4* __restrict__ c4,
    const float* __restrict__ scA, const float* __restrict__ shA,
    u16* __restrict__ C, float* __restrict__ psum, float* __restrict__ psumsq) {
  __shared__ u16 As[128 * 32];   // 8 KB, row r at As+r*32
  __shared__ u16 Bs[128 * 32];   // 8 KB
  int tid = threadIdx.x;
  int wave = tid >> 6, lane = tid & 63;
  int quad = lane >> 4, l16 = lane & 15;
  int m0 = blockIdx.x * 128, n0 = blockIdx.y * 128;
  int wm = (wave & 1) * 64, wn = (wave >> 1) * 64;
  int srow0 = lane >> 2;          // 0..15 within chunk
  int sc8 = (lane & 3) * 8;       // k-subcol *8
  f4v acc[4][4];
#pragma unroll
  for (int mi = 0; mi < 4; ++mi)
#pragma unroll
    for (int ni = 0; ni < 4; ++ni) acc[mi][ni] = (f4v){0.f, 0.f, 0.f, 0.f};

  for (int k0 = 0; k0 < K; k0 += 32) {
#pragma unroll
    for (int j = 0; j < 2; ++j) {
      int chunk = wave * 2 + j;
      int row = chunk * 16 + srow0;
      const u16* gA = A + (size_t)(m0 + row) * lda + k0 + sc8;
      const u16* gB = B + (size_t)(n0 + row) * ldb + k0 + sc8;
      if (APPLY_A) {
        uint4 av = *(const uint4*)gA;
        const u16* ap = (const u16*)&av;
        int kb = k0 + sc8;
        u32 outw[4];
#pragma unroll
        for (int t = 0; t < 4; ++t) {
          float x0 = fmaxf(fmaf(u2f(ap[2 * t]), scA[kb + 2 * t], shA[kb + 2 * t]), 0.f);
          float x1 = fmaxf(fmaf(u2f(ap[2 * t + 1]), scA[kb + 2 * t + 1], shA[kb + 2 * t + 1]), 0.f);
          outw[t] = packtrunc(x0, x1);
        }
        *(uint4*)&As[chunk * 512 + srow0 * 32 + sc8] = *(const uint4*)outw;
      } else {
        __builtin_amdgcn_global_load_lds(
            (const __attribute__((address_space(1))) void*)gA,
            (__attribute__((address_space(3))) void*)(As + chunk * 512), 16, 0, 0);
      }
      __builtin_amdgcn_global_load_lds(
          (const __attribute__((address_space(1))) void*)gB,
          (__attribute__((address_space(3))) void*)(Bs + chunk * 512), 16, 0, 0);
    }
    __syncthreads();
    s8v af[4], bfv[4];
#pragma unroll
    for (int mi = 0; mi < 4; ++mi)
      af[mi] = *(const s8v*)&As[(wm + mi * 16 + l16) * 32 + quad * 8];
#pragma unroll
    for (int ni = 0; ni < 4; ++ni)
      bfv[ni] = *(const s8v*)&Bs[(wn + ni * 16 + l16) * 32 + quad * 8];
#pragma unroll
    for (int mi = 0; mi < 4; ++mi)
#pragma unroll
      for (int ni = 0; ni < 4; ++ni)
        acc[mi][ni] = __builtin_amdgcn_mfma_f32_16x16x32_bf16(
            af[mi], bfv[ni], acc[mi][ni], 0, 0, 0);
    __syncthreads();
  }

  // epilogue + per-thread column partials
  int batch = m0 >> 12;
  float e0[4], e1[4], e2[4], e3[4];
  float ps[4] = {0, 0, 0, 0}, pq[4] = {0, 0, 0, 0};
#pragma unroll
  for (int ni = 0; ni < 4; ++ni) {
    int gn = n0 + wn + ni * 16 + l16;
    if (MODE1) {
      e0[ni] = zw[batch * 512 + gn];
      e1[ni] = u[gn];
      e2[ni] = u[512 + gn];
      e3[ni] = u[1024 + gn];
    } else {
      e0[ni] = bias[gn];
    }
  }
#pragma unroll
  for (int mi = 0; mi < 4; ++mi) {
#pragma unroll
    for (int reg = 0; reg < 4; ++reg) {
      int gm = m0 + wm + mi * 16 + quad * 4 + reg;
      float cx = 0.f, cy = 0.f, cz = 0.f;
      if (MODE1) {
        float4 p = c4[gm];
        cx = p.x; cy = p.y; cz = p.z;
      }
#pragma unroll
      for (int ni = 0; ni < 4; ++ni) {
        int gn = n0 + wn + ni * 16 + l16;
        float v = acc[mi][ni][reg] + e0[ni];
        if (MODE1) v += cx * e1[ni] + cy * e2[ni] + cz * e3[ni];
        u16 r = f2u(v);
        C[(size_t)gm * 512 + gn] = r;
        float vr = u2f(r);
        ps[ni] += vr;
        pq[ni] = fmaf(vr, vr, pq[ni]);
      }
    }
  }
  // block-level column reduction via LDS scratch (As=sum, Bs=sumsq)
  float* Lps = (float*)As;
  float* Lpq = (float*)Bs;
#pragma unroll
  for (int ni = 0; ni < 4; ++ni) {
    Lps[((wave * 4 + quad) * 4 + ni) * 16 + l16] = ps[ni];
    Lpq[((wave * 4 + quad) * 4 + ni) * 16 + l16] = pq[ni];
  }
  __syncthreads();
  if (tid < 128) {
    int wn2 = tid >> 6, rem = tid & 63;
    int nni = rem >> 4, ll = rem & 15;
    int gn = n0 + wn2 * 64 + nni * 16 + ll;
    float s = 0.f, q = 0.f;
#pragma unroll
    for (int wv = 0; wv < 2; ++wv)
#pragma unroll
      for (int qd = 0; qd < 4; ++qd) {
        int w2 = wn2 * 2 + wv;
        s += Lps[((w2 * 4 + qd) * 4 + nni) * 16 + ll];
        q += Lpq[((w2 * 4 + qd) * 4 + nni) * 16 + ll];
      }
    psum[(size_t)blockIdx.x * 512 + gn] = s;
    psumsq[(size_t)blockIdx.x * 512 + gn] = q;
  }
}

// ---------------------------------------------------------------------------
// BN stats: 2048 slabs x 16 rows (stage0 h1 only)
__global__ __launch_bounds__(256) void bn_stats_k(const u16* __restrict__ h,
                                                  float* __restrict__ psum,
                                                  float* __restrict__ psumsq) {
  int g = blockIdx.x;                 // 2048
  int c2 = threadIdx.x * 2;
  const u16* base = h + (size_t)g * 16 * 512;
  float s0 = 0, q0 = 0, s1 = 0, q1 = 0;
#pragma unroll
  for (int r = 0; r < 16; ++r) {
    u32 uu = *(const u32*)(base + (size_t)r * 512 + c2);
    float v0 = u2f((u16)(uu & 0xffffu));
    float v1 = u2f((u16)(uu >> 16));
    s0 += v0; q0 += v0 * v0;
    s1 += v1; q1 += v1 * v1;
  }
  psum[g * 512 + c2] = s0; psum[g * 512 + c2 + 1] = s1;
  psumsq[g * 512 + c2] = q0; psumsq[g * 512 + c2 + 1] = q1;
}

// BN finalize: wave-per-channel (512 waves), variable slab count
__global__ __launch_bounds__(256) void bn_fin_k(
    const float* __restrict__ psum, const float* __restrict__ psumsq, int nslabs,
    const float* __restrict__ gamma, const float* __restrict__ beta,
    float* __restrict__ sc, float* __restrict__ sh) {
  int c = blockIdx.x * 4 + (threadIdx.x >> 6);   // 0..511
  int lane = threadIdx.x & 63;
  float s = 0.f, q = 0.f;
  for (int g = lane; g < nslabs; g += 64) {
    s += psum[g * 512 + c];
    q += psumsq[g * 512 + c];
  }
#pragma unroll
  for (int off = 32; off; off >>= 1) {
    s += __shfl_down(s, off);
    q += __shfl_down(q, off);
  }
  if (lane == 0) {
    float mean = s * (1.f / 32768.f);
    float var = fmaxf(q * (1.f / 32768.f) - mean * mean, 0.f);
    float inv = rsqrtf(var + 1e-5f);
    float scale = gamma[c] * inv;
    sc[c] = scale;
    sh[c] = beta[c] - mean * scale;
  }
}

// ---------------------------------------------------------------------------
// layer3 (BN fused): coords = relu(h*sc+sh) @ w3^T + b3; wave per row
__global__ __launch_bounds__(256) void l3_k(const u16* __restrict__ h,
                                            const float* __restrict__ sc,
                                            const float* __restrict__ sh,
                                            const float* __restrict__ w3,
                                            const float* __restrict__ b3,
                                            float4* __restrict__ c4out,
                                            float* __restrict__ fout) {
  int wid = blockIdx.x * 4 + (threadIdx.x >> 6);
  int lane = threadIdx.x & 63;
  int k0 = lane * 8;
  uint4 hv = *(const uint4*)(h + (size_t)wid * 512 + k0);
  const u16* hp = (const u16*)&hv;
  float a0 = 0, a1 = 0, a2 = 0;
#pragma unroll
  for (int j = 0; j < 8; ++j) {
    int k = k0 + j;
    float x = fmaxf(fmaf(u2f(hp[j]), sc[k], sh[k]), 0.f);
    a0 = fmaf(x, w3[k], a0);
    a1 = fmaf(x, w3[512 + k], a1);
    a2 = fmaf(x, w3[1024 + k], a2);
  }
#pragma unroll
  for (int off = 32; off; off >>= 1) {
    a0 += __shfl_down(a0, off);
    a1 += __shfl_down(a1, off);
    a2 += __shfl_down(a2, off);
  }
  if (lane == 0) {
    a0 += b3[0]; a1 += b3[1]; a2 += b3[2];
    if (c4out) {
      float sq = a0 * a0 + a1 * a1 + a2 * a2;
      c4out[wid] = make_float4(a0, a1, a2, sq);
    }
    if (fout) {
      fout[(size_t)wid * 3 + 0] = a0;
      fout[(size_t)wid * 3 + 1] = a1;
      fout[(size_t)wid * 3 + 2] = a2;
    }
  }
}

// ---------------------------------------------------------------------------
// Attention: 8 queries per wave, unconditional predicated body (no skip —
// measured regressive). Per-query accumulation order identical to Q=4/Q=1
// versions -> bit-identical output.
__global__ __launch_bounds__(256) void attn_k(const float4* __restrict__ c4,
                                              const float* __restrict__ G,
                                              const float* __restrict__ wv,
                                              u16* __restrict__ attnb) {
  int wave = threadIdx.x >> 6, lane = threadIdx.x & 63;
  int qbase = (blockIdx.x * 4 + wave) * 8;    // 8 consecutive queries, same batch
  int b = qbase >> 12;
  const float4* cb = c4 + (size_t)b * NPTS;
  float cxq[8], cyq[8], czq[8], thrq[8], g0q[8], g1q[8], g2q[8];
#pragma unroll
  for (int q = 0; q < 8; ++q) {
    float4 cq = c4[qbase + q];
    cxq[q] = cq.x; cyq[q] = cq.y; czq[q] = cq.z;
    thrq[q] = 0.5f * (cq.w - R_ATT2);   // dot >= thr + 0.5*p.w  <=>  d2 <= R^2
    g0q[q] = (cq.x * G[0] + cq.y * G[3] + cq.z * G[6]) * INV_SQRT_D;
    g1q[q] = (cq.x * G[1] + cq.y * G[4] + cq.z * G[7]) * INV_SQRT_D;
    g2q[q] = (cq.x * G[2] + cq.y * G[5] + cq.z * G[8]) * INV_SQRT_D;
  }
  float swq[8] = {}, sxq[8] = {}, syq[8] = {}, szq[8] = {};

  for (int m0 = 0; m0 < NPTS; m0 += 64) {
    float4 p = cb[m0 + lane];
    float hw = 0.5f * p.w;
#pragma unroll
    for (int q = 0; q < 8; ++q) {
      float dot = fmaf(cxq[q], p.x, fmaf(cyq[q], p.y, czq[q] * p.z));
      float s = fmaf(g0q[q], p.x, fmaf(g1q[q], p.y, g2q[q] * p.z));
      float e = (dot >= thrq[q] + hw) ? __expf(s) : 0.f;
      swq[q] += e;
      sxq[q] = fmaf(e, p.x, sxq[q]);
      syq[q] = fmaf(e, p.y, syq[q]);
      szq[q] = fmaf(e, p.z, szq[q]);
    }
  }
#pragma unroll
  for (int q = 0; q < 8; ++q) {
#pragma unroll
    for (int off = 32; off; off >>= 1) {
      swq[q] += __shfl_xor(swq[q], off);
      sxq[q] += __shfl_xor(sxq[q], off);
      syq[q] += __shfl_xor(syq[q], off);
      szq[q] += __shfl_xor(szq[q], off);
    }
  }
  int d0 = lane * 2;
  float w0 = wv[d0 * 3], w1 = wv[d0 * 3 + 1], w2 = wv[d0 * 3 + 2];
  float w3_ = wv[d0 * 3 + 3], w4 = wv[d0 * 3 + 4], w5 = wv[d0 * 3 + 5];
#pragma unroll
  for (int q = 0; q < 8; ++q) {
    float inv = 1.f / swq[q];           // >=~1 always (self passes mask)
    float ox = sxq[q] * inv, oy = syq[q] * inv, oz = szq[q] * inv;
    float v0 = ox * w0 + oy * w1 + oz * w2;
    float v1 = ox * w3_ + oy * w4 + oz * w5;
    u32 pack = (u32)f2u(v0) | ((u32)f2u(v1) << 16);
    *(u32*)(attnb + (size_t)(qbase + q) * 128 + d0) = pack;
  }
}

// ---------------------------------------------------------------------------
extern "C" void kernel_launch(void* const* d_in, const int* in_sizes, int n_in,
                              void* d_out, int out_size, void* d_ws, size_t ws_size,
                              hipStream_t stream) {
  const float* z = (const float*)d_in[0];
  const float* tmpl = (const float*)d_in[1];
  const float* wq = (const float*)d_in[2];
  const float* wk = (const float*)d_in[3];
  const float* wv = (const float*)d_in[4];
  const float* sw[3][10];
  for (int s = 0; s < 3; ++s)
    for (int j = 0; j < 10; ++j) sw[s][j] = (const float*)d_in[5 + s * 10 + j];
  // j: 0=w1 1=b1 2=g1 3=be1 4=w2 5=b2 6=g2 7=be2 8=w3 9=b3

  char* base = (char*)d_ws;
  size_t off = 0;
  auto alloc = [&](size_t bytes) -> void* {
    void* p = base + off;
    off = (off + bytes + 255) & ~(size_t)255;
    return p;
  };
  u16* hA = (u16*)alloc((size_t)ROWS * 512 * 2);        // 33.55 MB
  u16* hB = (u16*)alloc((size_t)ROWS * 512 * 2);        // 33.55 MB
  u16* attnb = (u16*)alloc((size_t)ROWS * 128 * 2);     //  8.39 MB
  float4* c4 = (float4*)alloc((size_t)ROWS * 16);       //  0.52 MB
  float* psum = (float*)alloc(2048 * 512 * 4);          //  4.19 MB (dedicated)
  float* psumsq = (float*)alloc(2048 * 512 * 4);        //  4.19 MB
  float* zwbuf = (float*)alloc(4096 * 4);
  float* scv = (float*)alloc(512 * 4);
  float* shv = (float*)alloc(512 * 4);
  float* G = (float*)alloc(256);
  u16* w1abf = (u16*)alloc(512 * 128 * 2);
  u16* w2bf = (u16*)alloc(512 * 512 * 2);
  float* ubuf = (float*)alloc(1536 * 4);
  // total ~85 MB; ws >= 154 MB confirmed (round-6 fp32 branch ran)

  gram_k<<<1, 64, 0, stream>>>(wq, wk, G);

  for (int s = 0; s < 3; ++s) {
    int ldw = (s == 0) ? 515 : 643;
    prep2_k<<<1024, 256, 0, stream>>>(z, sw[s][0], ldw, sw[s][1], sw[s][4],
                                      zwbuf, ubuf, w1abf, w2bf, s == 0 ? 0 : 1);
    if (s == 0) {
      s0l1_k<<<8192, 256, 0, stream>>>(tmpl, ubuf, zwbuf, hA);
      bn_stats_k<<<2048, 256, 0, stream>>>(hA, psum, psumsq);
      bn_fin_k<<<128, 256, 0, stream>>>(psum, psumsq, 2048,
                                        sw[s][2], sw[s][3], scv, shv);
    } else {
      // GEMM1: h1 = attnb @ w1a^T + (zw + coords-rank3); fused h1 stats
      gemm_mfma_k<true, false><<<dim3(256, 4), 256, 0, stream>>>(
          attnb, 128, w1abf, 128, 128, nullptr, zwbuf, ubuf, c4,
          nullptr, nullptr, hA, psum, psumsq);
      bn_fin_k<<<128, 256, 0, stream>>>(psum, psumsq, 256,
                                        sw[s][2], sw[s][3], scv, shv);
    }
    // GEMM2: h2 = relu(BN(h1)) @ w2^T + b2, BN+ReLU fused in A-staging
    // (trunc-pack), fused h2 stats. Reads hA, writes hB.
    gemm_mfma_k<false, true><<<dim3(256, 4), 256, 0, stream>>>(
        hA, 512, w2bf, 512, 512, sw[s][5], nullptr, nullptr, nullptr,
        scv, shv, hB, psum, psumsq);
    bn_fin_k<<<128, 256, 0, stream>>>(psum, psumsq, 256,
                                      sw[s][6], sw[s][7], scv, shv);
    bool last = (s == 2);
    l3_k<<<8192, 256, 0, stream>>>(hB, scv, shv, sw[s][8], sw[s][9],
                                   last ? nullptr : c4,
                                   last ? (float*)d_out : nullptr);
    if (!last) {
      attn_k<<<1024, 256, 0, stream>>>(c4, G, wv, attnb);
    }
  }
}

// Round 21
// 519.728 us; speedup vs baseline: 1.0327x; 1.0327x over previous
//
#include <hip/hip_runtime.h>
#include <math.h>

#define NPTS 4096
#define BATCH 8
#define HIDD 512
#define ROWS 32768
#define R_ATT2 0.04f
#define INV_SQRT_D 0.08838834764831845f

typedef unsigned short u16;
typedef unsigned int u32;
typedef __attribute__((ext_vector_type(8))) short s8v;
typedef __attribute__((ext_vector_type(4))) float f4v;

__device__ __forceinline__ float u2f(u16 v) { return __uint_as_float(((u32)v) << 16); }
__device__ __forceinline__ u16 f2u(float f) {         // RNE fp32->bf16
  u32 u = __float_as_uint(f);
  return (u16)((u + 0x7fffu + ((u >> 16) & 1u)) >> 16);
}
// trunc-pack two fp32 into packed bf16 pair (1 lshr + 1 and_or)
__device__ __forceinline__ u32 packtrunc(float x0, float x1) {
  return (__float_as_uint(x1) & 0xFFFF0000u) | (__float_as_uint(x0) >> 16);
}

// ---------------------------------------------------------------------------
// G = wq^T @ wk (3x3)
__global__ void gram_k(const float* __restrict__ wq, const float* __restrict__ wk,
                       float* __restrict__ G) {
  int ab = threadIdx.x;
  if (ab < 9) {
    int a = ab / 3, b = ab % 3;
    float s = 0.f;
    for (int d = 0; d < 128; ++d) s = fmaf(wq[d * 3 + a], wk[d * 3 + b], s);
    G[ab] = s;
  }
}

// Fused per-stage prep: zw (wave-per-output) + ubuf/w1abf/w2bf conversions.
__global__ __launch_bounds__(256) void prep2_k(
    const float* __restrict__ z, const float* __restrict__ w1, int ldw,
    const float* __restrict__ b1, const float* __restrict__ w2,
    float* __restrict__ zwbuf, float* __restrict__ ubuf,
    u16* __restrict__ w1abf, u16* __restrict__ w2bf, int doW1a) {
  int wid = blockIdx.x * 4 + (threadIdx.x >> 6);   // 0..4095
  int lane = threadIdx.x & 63;
  {
    int b = wid >> 9, c = wid & 511;
    const float* zr = z + b * 512;
    const float* wr = w1 + (size_t)c * ldw;
    float acc = 0.f;
#pragma unroll
    for (int k = lane; k < 512; k += 64) acc = fmaf(zr[k], wr[k], acc);
#pragma unroll
    for (int off = 32; off; off >>= 1) acc += __shfl_down(acc, off);
    if (lane == 0) zwbuf[wid] = acc + b1[c];
  }
  int idx = blockIdx.x * 256 + threadIdx.x;        // 1024 blocks = 262144
  if (idx < 1536) {
    int a = idx >> 9, c = idx & 511;
    ubuf[idx] = w1[(size_t)c * ldw + 512 + a];
  }
  if (doW1a && idx < 65536) {
    int n = idx >> 7, k = idx & 127;
    w1abf[idx] = f2u(w1[(size_t)n * 643 + 515 + k]);
  }
  w2bf[idx] = f2u(w2[idx]);
}

// stage0 layer1: wave-per-row, vectorized loads + uint4 trunc-pack store
__global__ __launch_bounds__(256) void s0l1_k(const float* __restrict__ tmpl,
                                              const float* __restrict__ u,
                                              const float* __restrict__ zw,
                                              u16* __restrict__ h) {
  int wid = blockIdx.x * 4 + (threadIdx.x >> 6);   // row 0..32767
  int lane = threadIdx.x & 63;
  int b = wid >> 12, n = wid & (NPTS - 1);
  float tx = tmpl[n * 3], ty = tmpl[n * 3 + 1], tz = tmpl[n * 3 + 2];
  int c0 = lane * 8;
  const float* zr = zw + b * 512 + c0;
  const float* u0 = u + c0;
  const float* u1 = u + 512 + c0;
  const float* u2 = u + 1024 + c0;
  u32 outw[4];
#pragma unroll
  for (int t = 0; t < 4; ++t) {
    float v0 = zr[2 * t] + tx * u0[2 * t] + ty * u1[2 * t] + tz * u2[2 * t];
    float v1 = zr[2 * t + 1] + tx * u0[2 * t + 1] + ty * u1[2 * t + 1] + tz * u2[2 * t + 1];
    outw[t] = packtrunc(v0, v1);
  }
  *(uint4*)(h + (size_t)wid * 512 + c0) = *(const uint4*)outw;
}

// ---------------------------------------------------------------------------
// MFMA GEMM (BK=32, 16 KB LDS — occupancy-optimal; BK=64 measured -31 us).
// Fused BN-stats epilogue; optional fused BN+ReLU on A (trunc-pack).
template <bool MODE1, bool APPLY_A>
__global__ __launch_bounds__(256) void gemm_mfma_k(
    const u16* __restrict__ A, int lda, const u16* __restrict__ B, int ldb, int K,
    const float* __restrict__ bias, const float* __restrict__ zw,
    const float* __restrict__ u, const float4* __restrict__ c4,
    const float* __restrict__ scA, const float* __restrict__ shA,
    u16* __restrict__ C, float* __restrict__ psum, float* __restrict__ psumsq) {
  __shared__ u16 As[128 * 32];   // 8 KB, row r at As+r*32
  __shared__ u16 Bs[128 * 32];   // 8 KB
  int tid = threadIdx.x;
  int wave = tid >> 6, lane = tid & 63;
  int quad = lane >> 4, l16 = lane & 15;
  int m0 = blockIdx.x * 128, n0 = blockIdx.y * 128;
  int wm = (wave & 1) * 64, wn = (wave >> 1) * 64;
  int srow0 = lane >> 2;          // 0..15 within chunk
  int sc8 = (lane & 3) * 8;       // k-subcol *8
  f4v acc[4][4];
#pragma unroll
  for (int mi = 0; mi < 4; ++mi)
#pragma unroll
    for (int ni = 0; ni < 4; ++ni) acc[mi][ni] = (f4v){0.f, 0.f, 0.f, 0.f};

  for (int k0 = 0; k0 < K; k0 += 32) {
#pragma unroll
    for (int j = 0; j < 2; ++j) {
      int chunk = wave * 2 + j;
      int row = chunk * 16 + srow0;
      const u16* gA = A + (size_t)(m0 + row) * lda + k0 + sc8;
      const u16* gB = B + (size_t)(n0 + row) * ldb + k0 + sc8;
      if (APPLY_A) {
        uint4 av = *(const uint4*)gA;
        const u16* ap = (const u16*)&av;
        int kb = k0 + sc8;
        u32 outw[4];
#pragma unroll
        for (int t = 0; t < 4; ++t) {
          float x0 = fmaxf(fmaf(u2f(ap[2 * t]), scA[kb + 2 * t], shA[kb + 2 * t]), 0.f);
          float x1 = fmaxf(fmaf(u2f(ap[2 * t + 1]), scA[kb + 2 * t + 1], shA[kb + 2 * t + 1]), 0.f);
          outw[t] = packtrunc(x0, x1);
        }
        *(uint4*)&As[chunk * 512 + srow0 * 32 + sc8] = *(const uint4*)outw;
      } else {
        __builtin_amdgcn_global_load_lds(
            (const __attribute__((address_space(1))) void*)gA,
            (__attribute__((address_space(3))) void*)(As + chunk * 512), 16, 0, 0);
      }
      __builtin_amdgcn_global_load_lds(
          (const __attribute__((address_space(1))) void*)gB,
          (__attribute__((address_space(3))) void*)(Bs + chunk * 512), 16, 0, 0);
    }
    __syncthreads();
    s8v af[4], bfv[4];
#pragma unroll
    for (int mi = 0; mi < 4; ++mi)
      af[mi] = *(const s8v*)&As[(wm + mi * 16 + l16) * 32 + quad * 8];
#pragma unroll
    for (int ni = 0; ni < 4; ++ni)
      bfv[ni] = *(const s8v*)&Bs[(wn + ni * 16 + l16) * 32 + quad * 8];
#pragma unroll
    for (int mi = 0; mi < 4; ++mi)
#pragma unroll
      for (int ni = 0; ni < 4; ++ni)
        acc[mi][ni] = __builtin_amdgcn_mfma_f32_16x16x32_bf16(
            af[mi], bfv[ni], acc[mi][ni], 0, 0, 0);
    __syncthreads();
  }

  // epilogue + per-thread column partials
  int batch = m0 >> 12;
  float e0[4], e1[4], e2[4], e3[4];
  float ps[4] = {0, 0, 0, 0}, pq[4] = {0, 0, 0, 0};
#pragma unroll
  for (int ni = 0; ni < 4; ++ni) {
    int gn = n0 + wn + ni * 16 + l16;
    if (MODE1) {
      e0[ni] = zw[batch * 512 + gn];
      e1[ni] = u[gn];
      e2[ni] = u[512 + gn];
      e3[ni] = u[1024 + gn];
    } else {
      e0[ni] = bias[gn];
    }
  }
#pragma unroll
  for (int mi = 0; mi < 4; ++mi) {
#pragma unroll
    for (int reg = 0; reg < 4; ++reg) {
      int gm = m0 + wm + mi * 16 + quad * 4 + reg;
      float cx = 0.f, cy = 0.f, cz = 0.f;
      if (MODE1) {
        float4 p = c4[gm];
        cx = p.x; cy = p.y; cz = p.z;
      }
#pragma unroll
      for (int ni = 0; ni < 4; ++ni) {
        int gn = n0 + wn + ni * 16 + l16;
        float v = acc[mi][ni][reg] + e0[ni];
        if (MODE1) v += cx * e1[ni] + cy * e2[ni] + cz * e3[ni];
        u16 r = f2u(v);
        C[(size_t)gm * 512 + gn] = r;
        float vr = u2f(r);
        ps[ni] += vr;
        pq[ni] = fmaf(vr, vr, pq[ni]);
      }
    }
  }
  // block-level column reduction via LDS scratch (As=sum, Bs=sumsq)
  float* Lps = (float*)As;
  float* Lpq = (float*)Bs;
#pragma unroll
  for (int ni = 0; ni < 4; ++ni) {
    Lps[((wave * 4 + quad) * 4 + ni) * 16 + l16] = ps[ni];
    Lpq[((wave * 4 + quad) * 4 + ni) * 16 + l16] = pq[ni];
  }
  __syncthreads();
  if (tid < 128) {
    int wn2 = tid >> 6, rem = tid & 63;
    int nni = rem >> 4, ll = rem & 15;
    int gn = n0 + wn2 * 64 + nni * 16 + ll;
    float s = 0.f, q = 0.f;
#pragma unroll
    for (int wv = 0; wv < 2; ++wv)
#pragma unroll
      for (int qd = 0; qd < 4; ++qd) {
        int w2 = wn2 * 2 + wv;
        s += Lps[((w2 * 4 + qd) * 4 + nni) * 16 + ll];
        q += Lpq[((w2 * 4 + qd) * 4 + nni) * 16 + ll];
      }
    psum[(size_t)blockIdx.x * 512 + gn] = s;
    psumsq[(size_t)blockIdx.x * 512 + gn] = q;
  }
}

// ---------------------------------------------------------------------------
// BN stats: 2048 slabs x 16 rows (stage0 h1 only)
__global__ __launch_bounds__(256) void bn_stats_k(const u16* __restrict__ h,
                                                  float* __restrict__ psum,
                                                  float* __restrict__ psumsq) {
  int g = blockIdx.x;                 // 2048
  int c2 = threadIdx.x * 2;
  const u16* base = h + (size_t)g * 16 * 512;
  float s0 = 0, q0 = 0, s1 = 0, q1 = 0;
#pragma unroll
  for (int r = 0; r < 16; ++r) {
    u32 uu = *(const u32*)(base + (size_t)r * 512 + c2);
    float v0 = u2f((u16)(uu & 0xffffu));
    float v1 = u2f((u16)(uu >> 16));
    s0 += v0; q0 += v0 * v0;
    s1 += v1; q1 += v1 * v1;
  }
  psum[g * 512 + c2] = s0; psum[g * 512 + c2 + 1] = s1;
  psumsq[g * 512 + c2] = q0; psumsq[g * 512 + c2 + 1] = q1;
}

// BN finalize: wave-per-channel (512 waves), variable slab count
__global__ __launch_bounds__(256) void bn_fin_k(
    const float* __restrict__ psum, const float* __restrict__ psumsq, int nslabs,
    const float* __restrict__ gamma, const float* __restrict__ beta,
    float* __restrict__ sc, float* __restrict__ sh) {
  int c = blockIdx.x * 4 + (threadIdx.x >> 6);   // 0..511
  int lane = threadIdx.x & 63;
  float s = 0.f, q = 0.f;
  for (int g = lane; g < nslabs; g += 64) {
    s += psum[g * 512 + c];
    q += psumsq[g * 512 + c];
  }
#pragma unroll
  for (int off = 32; off; off >>= 1) {
    s += __shfl_down(s, off);
    q += __shfl_down(q, off);
  }
  if (lane == 0) {
    float mean = s * (1.f / 32768.f);
    float var = fmaxf(q * (1.f / 32768.f) - mean * mean, 0.f);
    float inv = rsqrtf(var + 1e-5f);
    float scale = gamma[c] * inv;
    sc[c] = scale;
    sh[c] = beta[c] - mean * scale;
  }
}

// ---------------------------------------------------------------------------
// layer3 (BN fused): coords = relu(h*sc+sh) @ w3^T + b3; wave per row
__global__ __launch_bounds__(256) void l3_k(const u16* __restrict__ h,
                                            const float* __restrict__ sc,
                                            const float* __restrict__ sh,
                                            const float* __restrict__ w3,
                                            const float* __restrict__ b3,
                                            float4* __restrict__ c4out,
                                            float* __restrict__ fout) {
  int wid = blockIdx.x * 4 + (threadIdx.x >> 6);
  int lane = threadIdx.x & 63;
  int k0 = lane * 8;
  uint4 hv = *(const uint4*)(h + (size_t)wid * 512 + k0);
  const u16* hp = (const u16*)&hv;
  float a0 = 0, a1 = 0, a2 = 0;
#pragma unroll
  for (int j = 0; j < 8; ++j) {
    int k = k0 + j;
    float x = fmaxf(fmaf(u2f(hp[j]), sc[k], sh[k]), 0.f);
    a0 = fmaf(x, w3[k], a0);
    a1 = fmaf(x, w3[512 + k], a1);
    a2 = fmaf(x, w3[1024 + k], a2);
  }
#pragma unroll
  for (int off = 32; off; off >>= 1) {
    a0 += __shfl_down(a0, off);
    a1 += __shfl_down(a1, off);
    a2 += __shfl_down(a2, off);
  }
  if (lane == 0) {
    a0 += b3[0]; a1 += b3[1]; a2 += b3[2];
    if (c4out) {
      float sq = a0 * a0 + a1 * a1 + a2 * a2;
      c4out[wid] = make_float4(a0, a1, a2, sq);
    }
    if (fout) {
      fout[(size_t)wid * 3 + 0] = a0;
      fout[(size_t)wid * 3 + 1] = a1;
      fout[(size_t)wid * 3 + 2] = a2;
    }
  }
}

// ---------------------------------------------------------------------------
// Attention: 4 queries per wave (measured occupancy-optimal: Q=1 79.5us,
// Q=4 62.1us, Q=8 67.1us), unconditional predicated body (skip measured
// regressive), __expf (poly measured regressive).
__global__ __launch_bounds__(256) void attn_k(const float4* __restrict__ c4,
                                              const float* __restrict__ G,
                                              const float* __restrict__ wv,
                                              u16* __restrict__ attnb) {
  int wave = threadIdx.x >> 6, lane = threadIdx.x & 63;
  int qbase = (blockIdx.x * 4 + wave) * 4;    // 4 consecutive queries, same batch
  int b = qbase >> 12;
  const float4* cb = c4 + (size_t)b * NPTS;
  float cxq[4], cyq[4], czq[4], thrq[4], g0q[4], g1q[4], g2q[4];
#pragma unroll
  for (int q = 0; q < 4; ++q) {
    float4 cq = c4[qbase + q];
    cxq[q] = cq.x; cyq[q] = cq.y; czq[q] = cq.z;
    thrq[q] = 0.5f * (cq.w - R_ATT2);   // dot >= thr + 0.5*p.w  <=>  d2 <= R^2
    g0q[q] = (cq.x * G[0] + cq.y * G[3] + cq.z * G[6]) * INV_SQRT_D;
    g1q[q] = (cq.x * G[1] + cq.y * G[4] + cq.z * G[7]) * INV_SQRT_D;
    g2q[q] = (cq.x * G[2] + cq.y * G[5] + cq.z * G[8]) * INV_SQRT_D;
  }
  float swq[4] = {0, 0, 0, 0}, sxq[4] = {0, 0, 0, 0};
  float syq[4] = {0, 0, 0, 0}, szq[4] = {0, 0, 0, 0};

  for (int m0 = 0; m0 < NPTS; m0 += 64) {
    float4 p = cb[m0 + lane];
    float hw = 0.5f * p.w;
#pragma unroll
    for (int q = 0; q < 4; ++q) {
      float dot = fmaf(cxq[q], p.x, fmaf(cyq[q], p.y, czq[q] * p.z));
      float s = fmaf(g0q[q], p.x, fmaf(g1q[q], p.y, g2q[q] * p.z));
      float e = (dot >= thrq[q] + hw) ? __expf(s) : 0.f;
      swq[q] += e;
      sxq[q] = fmaf(e, p.x, sxq[q]);
      syq[q] = fmaf(e, p.y, syq[q]);
      szq[q] = fmaf(e, p.z, szq[q]);
    }
  }
#pragma unroll
  for (int q = 0; q < 4; ++q) {
#pragma unroll
    for (int off = 32; off; off >>= 1) {
      swq[q] += __shfl_xor(swq[q], off);
      sxq[q] += __shfl_xor(sxq[q], off);
      syq[q] += __shfl_xor(syq[q], off);
      szq[q] += __shfl_xor(szq[q], off);
    }
  }
  int d0 = lane * 2;
  float w0 = wv[d0 * 3], w1 = wv[d0 * 3 + 1], w2 = wv[d0 * 3 + 2];
  float w3_ = wv[d0 * 3 + 3], w4 = wv[d0 * 3 + 4], w5 = wv[d0 * 3 + 5];
#pragma unroll
  for (int q = 0; q < 4; ++q) {
    float inv = 1.f / swq[q];           // >=~1 always (self passes mask)
    float ox = sxq[q] * inv, oy = syq[q] * inv, oz = szq[q] * inv;
    float v0 = ox * w0 + oy * w1 + oz * w2;
    float v1 = ox * w3_ + oy * w4 + oz * w5;
    u32 pack = (u32)f2u(v0) | ((u32)f2u(v1) << 16);
    *(u32*)(attnb + (size_t)(qbase + q) * 128 + d0) = pack;
  }
}

// ---------------------------------------------------------------------------
extern "C" void kernel_launch(void* const* d_in, const int* in_sizes, int n_in,
                              void* d_out, int out_size, void* d_ws, size_t ws_size,
                              hipStream_t stream) {
  const float* z = (const float*)d_in[0];
  const float* tmpl = (const float*)d_in[1];
  const float* wq = (const float*)d_in[2];
  const float* wk = (const float*)d_in[3];
  const float* wv = (const float*)d_in[4];
  const float* sw[3][10];
  for (int s = 0; s < 3; ++s)
    for (int j = 0; j < 10; ++j) sw[s][j] = (const float*)d_in[5 + s * 10 + j];
  // j: 0=w1 1=b1 2=g1 3=be1 4=w2 5=b2 6=g2 7=be2 8=w3 9=b3

  char* base = (char*)d_ws;
  size_t off = 0;
  auto alloc = [&](size_t bytes) -> void* {
    void* p = base + off;
    off = (off + bytes + 255) & ~(size_t)255;
    return p;
  };
  u16* hA = (u16*)alloc((size_t)ROWS * 512 * 2);        // 33.55 MB
  u16* hB = (u16*)alloc((size_t)ROWS * 512 * 2);        // 33.55 MB
  u16* attnb = (u16*)alloc((size_t)ROWS * 128 * 2);     //  8.39 MB
  float4* c4 = (float4*)alloc((size_t)ROWS * 16);       //  0.52 MB
  float* psum = (float*)alloc(2048 * 512 * 4);          //  4.19 MB (dedicated)
  float* psumsq = (float*)alloc(2048 * 512 * 4);        //  4.19 MB
  float* zwbuf = (float*)alloc(4096 * 4);
  float* scv = (float*)alloc(512 * 4);
  float* shv = (float*)alloc(512 * 4);
  float* G = (float*)alloc(256);
  u16* w1abf = (u16*)alloc(512 * 128 * 2);
  u16* w2bf = (u16*)alloc(512 * 512 * 2);
  float* ubuf = (float*)alloc(1536 * 4);
  // total ~85 MB; ws >= 154 MB confirmed (round-6 fp32 branch ran)

  gram_k<<<1, 64, 0, stream>>>(wq, wk, G);

  for (int s = 0; s < 3; ++s) {
    int ldw = (s == 0) ? 515 : 643;
    prep2_k<<<1024, 256, 0, stream>>>(z, sw[s][0], ldw, sw[s][1], sw[s][4],
                                      zwbuf, ubuf, w1abf, w2bf, s == 0 ? 0 : 1);
    if (s == 0) {
      s0l1_k<<<8192, 256, 0, stream>>>(tmpl, ubuf, zwbuf, hA);
      bn_stats_k<<<2048, 256, 0, stream>>>(hA, psum, psumsq);
      bn_fin_k<<<128, 256, 0, stream>>>(psum, psumsq, 2048,
                                        sw[s][2], sw[s][3], scv, shv);
    } else {
      // GEMM1: h1 = attnb @ w1a^T + (zw + coords-rank3); fused h1 stats
      gemm_mfma_k<true, false><<<dim3(256, 4), 256, 0, stream>>>(
          attnb, 128, w1abf, 128, 128, nullptr, zwbuf, ubuf, c4,
          nullptr, nullptr, hA, psum, psumsq);
      bn_fin_k<<<128, 256, 0, stream>>>(psum, psumsq, 256,
                                        sw[s][2], sw[s][3], scv, shv);
    }
    // GEMM2: h2 = relu(BN(h1)) @ w2^T + b2, BN+ReLU fused in A-staging
    // (trunc-pack), fused h2 stats. Reads hA, writes hB.
    gemm_mfma_k<false, true><<<dim3(256, 4), 256, 0, stream>>>(
        hA, 512, w2bf, 512, 512, sw[s][5], nullptr, nullptr, nullptr,
        scv, shv, hB, psum, psumsq);
    bn_fin_k<<<128, 256, 0, stream>>>(psum, psumsq, 256,
                                      sw[s][6], sw[s][7], scv, shv);
    bool last = (s == 2);
    l3_k<<<8192, 256, 0, stream>>>(hB, scv, shv, sw[s][8], sw[s][9],
                                   last ? nullptr : c4,
                                   last ? (float*)d_out : nullptr);
    if (!last) {
      attn_k<<<2048, 256, 0, stream>>>(c4, G, wv, attnb);
    }
  }
}